// Round 10
// baseline (91.254 us; speedup 1.0000x reference)
//
#include <hip/hip_runtime.h>

#define HID 768
#define NL  17
#define BB  64
#define TT  512

#define RB   32                 // rows per block
#define CK   128                // K-chunk (floats)
#define NCH  6                  // HID / CK
#define XS_F (RB * CK)          // 4096 floats per x buffer
#define WS_F (NL * CK)          // 2176 floats per w buffer
#define WBASE (2 * XS_F)        // w buffers start (floats)

// ===========================================================================
// Kernel 1: emissions = outputs @ fc_w^T + fc_b   (32768x768 @ 768^T x 17)
// 256 thr (4 waves), 32 rows/block, K in 6 chunks of 128. Staging via
// global_load_lds (width 16, compiler can't sink a DMA): x tile XOR-swizzled
// through a pre-swizzled GLOBAL source (LDS dest linear, rule #21), w chunk
// linear. Double-buffered: chunk c+1's loads issue before compute of c; one
// vmcnt(0)+barrier per chunk. Compute: lane = row(&31)+half, wave w owns 32
// cols/chunk; x via swizzled ds_read_b128 (conflict-free), w via uniform
// ds_read_b128 (broadcast). Split-8 partials reduced through reused LDS.
// ===========================================================================
__device__ __forceinline__ void gload16(const float* g, float* l) {
    __builtin_amdgcn_global_load_lds(
        (const __attribute__((address_space(1))) float*)g,
        (__attribute__((address_space(3))) float*)l, 16, 0, 0);
}

__global__ __launch_bounds__(256) void emis_kernel(const float* __restrict__ x,
                                                   const float* __restrict__ w,
                                                   const float* __restrict__ bias,
                                                   float* __restrict__ y) {
    __shared__ float smem[2 * XS_F + 2 * WS_F];   // 50.2 KB

    const int tid  = threadIdx.x;
    const int lane = tid & 63;
    const int wid  = tid >> 6;                    // 0..3
    const int wub  = tid & ~63;                   // wave-uniform thread base
    const size_t rowbase = (size_t)blockIdx.x * RB;

    // ---- staging: one K-chunk (x swizzled-source, w linear) into buf ----
#define STAGE(buf, c)                                                         \
    {                                                                         \
        _Pragma("unroll")                                                     \
        for (int i = 0; i < 4; ++i) {                                         \
            const int G = tid + 256 * i;          /* x granule 0..1023 */     \
            const int r = G >> 5, cg = G & 31;                                \
            gload16(x + (rowbase + r) * HID + (c) * CK + ((cg ^ (r & 7)) << 2), \
                    &smem[(buf) * XS_F + ((wub + 256 * i) << 2)]);            \
        }                                                                     \
        _Pragma("unroll")                                                     \
        for (int i = 0; i < 2; ++i) {                                         \
            const int G = tid + 256 * i;          /* w granule 0..511 */      \
            gload16(w + (G >> 5) * HID + (c) * CK + ((G & 31) << 2),          \
                    &smem[WBASE + (buf) * WS_F + ((wub + 256 * i) << 2)]);    \
        }                                                                     \
        if (tid < 32) {                           /* w granule 512..543 */    \
            const int G = 512 + tid;                                          \
            gload16(w + (G >> 5) * HID + (c) * CK + ((G & 31) << 2),          \
                    &smem[WBASE + (buf) * WS_F + 2048]);                      \
        }                                                                     \
    }

    float acc[NL];
#pragma unroll
    for (int k = 0; k < NL; ++k) acc[k] = 0.f;

    const int r   = lane & 31;                    // my row
    const int h   = lane >> 5;                    // half-wave
    const int swz = r & 7;
    const int gc0 = 8 * wid + 4 * h;              // my first col granule

    STAGE(0, 0);
    __syncthreads();                              // drains vmcnt(0)

    int buf = 0;
    for (int c = 0; c < NCH; ++c) {
        if (c + 1 < NCH) STAGE(buf ^ 1, c + 1);   // issue next chunk's DMA

        // x fragment: swizzled read -> banks spread by row (conflict-free)
        float4 xf[4];
#pragma unroll
        for (int u = 0; u < 4; ++u)
            xf[u] = *reinterpret_cast<const float4*>(
                &smem[buf * XS_F + r * CK + ((gc0 + u) ^ swz) * 4]);

#pragma unroll
        for (int k = 0; k < NL; ++k) {
            const float* wk = &smem[WBASE + buf * WS_F + k * CK + gc0 * 4];
            float s0 = 0.f, s1 = 0.f, s2 = 0.f, s3 = 0.f;
#pragma unroll
            for (int u = 0; u < 4; ++u) {
                const float4 wv = *reinterpret_cast<const float4*>(wk + 4 * u);
                s0 = fmaf(xf[u].x, wv.x, s0);
                s1 = fmaf(xf[u].y, wv.y, s1);
                s2 = fmaf(xf[u].z, wv.z, s2);
                s3 = fmaf(xf[u].w, wv.w, s3);
            }
            acc[k] += (s0 + s1) + (s2 + s3);
        }

        __syncthreads();                          // next-chunk DMA landed; readers done
        buf ^= 1;
    }
#undef STAGE

    // ---- split-8 reduce through reused LDS ----
    const int s = tid >> 5;                       // col-slice 0..7
#pragma unroll
    for (int k = 0; k < NL; ++k) smem[s * (NL * RB) + k * RB + r] = acc[k];
    __syncthreads();

    for (int o = tid; o < RB * NL; o += 256) {
        const int rr = o / NL, k = o - rr * NL;
        float sum = bias[k];
#pragma unroll
        for (int ss = 0; ss < 8; ++ss) sum += smem[ss * (NL * RB) + k * RB + rr];
        y[rowbase * NL + o] = sum;
    }
}

// ===========================================================================
// Kernel 2: CRF llh. One wave per batch, no LDS. Exp-domain scan; lane j<17
// streams em column j straight from global (L2/L3-hit), double-buffered 8
// steps ahead with exp applied at prefetch. Renorm = exponent extract+ldexp.
// ===========================================================================
__device__ __forceinline__ float bcast(float v, int i) {
    return __uint_as_float(__builtin_amdgcn_readlane(__float_as_uint(v), i));
}

#define CRF_BODY(eem, PN)  \
    { float q0, q1, q2, q3;                                               \
      q0 = bcast(p,  0) * et[0];  q1 = bcast(p,  1) * et[1];              \
      q2 = bcast(p,  2) * et[2];  q3 = bcast(p,  3) * et[3];              \
      q0 = fmaf(bcast(p,  4), et[4],  q0); q1 = fmaf(bcast(p,  5), et[5],  q1); \
      q2 = fmaf(bcast(p,  6), et[6],  q2); q3 = fmaf(bcast(p,  7), et[7],  q3); \
      q0 = fmaf(bcast(p,  8), et[8],  q0); q1 = fmaf(bcast(p,  9), et[9],  q1); \
      q2 = fmaf(bcast(p, 10), et[10], q2); q3 = fmaf(bcast(p, 11), et[11], q3); \
      q0 = fmaf(bcast(p, 12), et[12], q0); q1 = fmaf(bcast(p, 13), et[13], q1); \
      q2 = fmaf(bcast(p, 14), et[14], q2); q3 = fmaf(bcast(p, 15), et[15], q3); \
      q0 = fmaf(bcast(p, 16), et[16], q0);                                \
      PN = ((q0 + q1) + (q2 + q3)) * (eem); }

#define CRF_STEP(eem)      { float pn_; CRF_BODY(eem, pn_); p = pn_; }
#define CRF_STEPG(eem, tt) { float pn_; CRF_BODY(eem, pn_); p = ((tt) < len) ? pn_ : p; }

__global__ __launch_bounds__(64) void crf_kernel(const float* __restrict__ emis,
                                                 const float* __restrict__ st_,
                                                 const float* __restrict__ en_,
                                                 const float* __restrict__ tr_,
                                                 const int* __restrict__ labels,
                                                 const int* __restrict__ mask,
                                                 float* __restrict__ llh) {
    const int b = blockIdx.x;
    const int l = threadIdx.x;
    const float* eb = emis + (size_t)b * TT * NL;
    const int*   lb = labels + b * TT;

    // ---- sequence length (prefix mask) ----
    int lenp = 0;
#pragma unroll
    for (int m = 0; m < 8; ++m) lenp += (mask[b * TT + l + 64 * m] != 0);
#pragma unroll
    for (int off = 32; off; off >>= 1) lenp += __shfl_down(lenp, off);
    const int len = __shfl(lenp, 0);

    // ---- numerator ----
    float np = 0.f;
#pragma unroll
    for (int m = 0; m < 8; ++m) {
        const int t = l + 64 * m;
        int tag = lb[t]; if ((unsigned)tag >= NL) tag = 0;
        if (t < len) {
            if (t == 0) {
                np += st_[tag] + eb[tag];
            } else {
                int tp = lb[t - 1]; if ((unsigned)tp >= NL) tp = 0;
                np += tr_[tp * NL + tag] + eb[t * NL + tag];
            }
            if (t == len - 1) np += en_[tag];
        }
    }
#pragma unroll
    for (int off = 32; off; off >>= 1) np += __shfl_down(np, off);
    const float num = __shfl(np, 0);

    // ---- denominator: exp-domain forward scan ----
    const bool act = (l < NL);
    const int  j   = act ? l : 0;

    float et[NL];
#pragma unroll
    for (int i = 0; i < NL; ++i) et[i] = act ? __expf(tr_[i * NL + j]) : 0.f;

    float p = act ? __expf(st_[j] + eb[j]) : 0.f;
    int   Mi = 0;

    float cur[8];
#pragma unroll
    for (int i = 0; i < 8; ++i) cur[i] = __expf(eb[(1 + i) * NL + j]);

    for (int t0 = 1; t0 < len; t0 += 8) {
        float nx[8];
#pragma unroll
        for (int i = 0; i < 8; ++i) {
            int tn = t0 + 8 + i; tn = (tn < TT) ? tn : (TT - 1);
            nx[i] = eb[tn * NL + j];             // issue; consumed next group
        }
        if (t0 + 8 <= len) {
            CRF_STEP(cur[0]); CRF_STEP(cur[1]); CRF_STEP(cur[2]); CRF_STEP(cur[3]);
            CRF_STEP(cur[4]); CRF_STEP(cur[5]); CRF_STEP(cur[6]); CRF_STEP(cur[7]);
        } else {
            CRF_STEPG(cur[0], t0 + 0); CRF_STEPG(cur[1], t0 + 1);
            CRF_STEPG(cur[2], t0 + 2); CRF_STEPG(cur[3], t0 + 3);
            CRF_STEPG(cur[4], t0 + 4); CRF_STEPG(cur[5], t0 + 5);
            CRF_STEPG(cur[6], t0 + 6); CRF_STEPG(cur[7], t0 + 7);
        }
        // renorm by p0 via exponent extraction (no log/rcp on critical path)
        const unsigned pb = (unsigned)__builtin_amdgcn_readlane((int)__float_as_uint(p), 0);
        const int e = (int)(pb >> 23) - 127;
        Mi += e;
        p = ldexpf(p, -e);
#pragma unroll
        for (int i = 0; i < 8; ++i) cur[i] = __expf(nx[i]);
    }

    float v = act ? p * __expf(en_[j]) : 0.f;
#pragma unroll
    for (int off = 32; off; off >>= 1) v += __shfl_down(v, off);

    if (l == 0) {
        const float denom = (float)Mi * 0.6931471805599453f + __logf(v);
        llh[b] = num - denom;
    }
}

// ===========================================================================
// Kernel 3: loss = -mean(llh)
// ===========================================================================
__global__ __launch_bounds__(64) void loss_kernel(const float* __restrict__ llh,
                                                  float* __restrict__ loss) {
    float v = llh[threadIdx.x];
#pragma unroll
    for (int off = 32; off; off >>= 1) v += __shfl_down(v, off);
    if (threadIdx.x == 0) loss[0] = -(v * (1.0f / BB));
}

// ===========================================================================
extern "C" void kernel_launch(void* const* d_in, const int* in_sizes, int n_in,
                              void* d_out, int out_size, void* d_ws, size_t ws_size,
                              hipStream_t stream) {
    const float* outputs = (const float*)d_in[0];
    const float* fc_w    = (const float*)d_in[1];
    const float* fc_b    = (const float*)d_in[2];
    const float* start_t = (const float*)d_in[3];
    const float* end_t   = (const float*)d_in[4];
    const float* trans   = (const float*)d_in[5];
    const int*   labels  = (const int*)d_in[6];
    const int*   mask    = (const int*)d_in[7];

    float* emis = (float*)d_out;
    float* loss = emis + (size_t)BB * TT * NL;
    float* llh  = (float*)d_ws;

    emis_kernel<<<(BB * TT) / RB, 256, 0, stream>>>(outputs, fc_w, fc_b, emis);
    crf_kernel<<<BB, 64, 0, stream>>>(emis, start_t, end_t, trans, labels, mask, llh);
    loss_kernel<<<1, 64, 0, stream>>>(llh, loss);
}

// Round 11
// 89.426 us; speedup vs baseline: 1.0204x; 1.0204x over previous
//
#include <hip/hip_runtime.h>

#define HID 768
#define NL  17
#define BB  64
#define TT  512

#define RB   16                  // rows per block
#define CK   128                 // K-chunk (floats)
#define NCH  6                   // HID / CK
#define WFL  (NL * HID)          // 13056 floats: all of w in LDS
#define XTF  (RB * CK)           // 2048 floats per x buffer
#define XOFF WFL                 // x buffers follow w

// ===========================================================================
// Kernel 1: emissions = outputs @ fc_w^T + fc_b   (32768x768 @ 768^T x 17)
// 256 thr (4 waves), 16 rows/block, grid 2048 (2 blocks/CU, 76.8 KB LDS).
// w staged ONCE (linear, reads are 4-way multicast on distinct banks); x in
// 6 chunks via global_load_lds, 3-deep buffer, pre-swizzled source (rule #21)
// so lane=row ds_read_b128 spreads uniformly over banks. T3/T4: raw s_barrier
// + counted vmcnt(4) — loads stay in flight across barriers, NEVER drained
// to 0 in the loop (R10's __syncthreads vmcnt(0) drain was the stall).
// Thread (r = tid&15, g = tid>>4) owns cols {c*128 + g*8 .. +8} of each chunk;
// split-16 partials reduced through reused x-buffer LDS.
// ===========================================================================
__device__ __forceinline__ void gload16(const float* g, float* l) {
    __builtin_amdgcn_global_load_lds(
        (const __attribute__((address_space(1))) float*)g,
        (__attribute__((address_space(3))) float*)l, 16, 0, 0);
}

__global__ __launch_bounds__(256) void emis_kernel(const float* __restrict__ x,
                                                   const float* __restrict__ w,
                                                   const float* __restrict__ bias,
                                                   float* __restrict__ y) {
    __shared__ float smem[WFL + 3 * XTF];     // 76.8 KB

    const int tid = threadIdx.x;
    const int wub = tid & ~63;                // wave-uniform base (DMA dest)
    const size_t rowbase = (size_t)blockIdx.x * RB;

    // ---- stage all of w, linear (3264 granules; wave 3 skips the 13th) ----
#pragma unroll
    for (int j = 0; j < 13; ++j) {
        const int G = tid + 256 * j;
        if (G < WFL / 4)
            gload16(w + 4 * (size_t)G, &smem[4 * (wub + 256 * j)]);
    }
    __builtin_amdgcn_sched_barrier(0);

#define XSTAGE(buf, c)                                                        \
    {                                                                         \
        _Pragma("unroll")                                                     \
        for (int i = 0; i < 2; ++i) {                                         \
            const int d = tid + 256 * i;                                      \
            const int rr_ = d >> 5, jg = d & 31;                              \
            gload16(x + (rowbase + rr_) * HID + (c) * CK + ((jg ^ (rr_ & 7)) << 2), \
                    &smem[XOFF + (buf) * XTF + 4 * (wub + 256 * i)]);         \
        }                                                                     \
        __builtin_amdgcn_sched_barrier(0);                                    \
    }

    XSTAGE(0, 0) XSTAGE(1, 1) XSTAGE(2, 2)    // 3-deep prologue

    float acc[NL];
#pragma unroll
    for (int k = 0; k < NL; ++k) acc[k] = 0.f;

    const int r = tid & 15;                   // my row
    const int g = tid >> 4;                   // my col-group 0..15
    const int q = r & 7;                      // swizzle key

    asm volatile("s_waitcnt vmcnt(4)" ::: "memory");   // w + x0 landed
    __builtin_amdgcn_s_barrier();
    asm volatile("" ::: "memory");

#define COMPUTE(c, buf)                                                       \
    {                                                                         \
        const float* xb = &smem[XOFF + (buf) * XTF + r * CK];                 \
        const float4 xf0 = *reinterpret_cast<const float4*>(xb + (((2 * g)     ^ q) << 2)); \
        const float4 xf1 = *reinterpret_cast<const float4*>(xb + (((2 * g + 1) ^ q) << 2)); \
        _Pragma("unroll")                                                     \
        for (int k = 0; k < NL; ++k) {                                        \
            const float* wk = &smem[k * HID + (c) * CK + g * 8];              \
            const float4 wa = *reinterpret_cast<const float4*>(wk);           \
            const float4 wc = *reinterpret_cast<const float4*>(wk + 4);       \
            float s0 = fmaf(xf0.x, wa.x, acc[k]);                             \
            float s1 = xf0.y * wa.y;                                          \
            s0 = fmaf(xf0.z, wa.z, s0);                                       \
            s1 = fmaf(xf0.w, wa.w, s1);                                       \
            s0 = fmaf(xf1.x, wc.x, s0);                                       \
            s1 = fmaf(xf1.y, wc.y, s1);                                       \
            s0 = fmaf(xf1.z, wc.z, s0);                                       \
            s1 = fmaf(xf1.w, wc.w, s1);                                       \
            acc[k] = s0 + s1;                                                 \
        }                                                                     \
    }

    // ---- steady loop (unrolled; buf static; vmcnt counted, never 0) ----
    COMPUTE(0, 0)
    asm volatile("" ::: "memory");
    __builtin_amdgcn_s_barrier();             // buf0 readers done
    XSTAGE(0, 3)
    asm volatile("s_waitcnt vmcnt(4)" ::: "memory");   // x1 landed
    __builtin_amdgcn_s_barrier();
    asm volatile("" ::: "memory");

    COMPUTE(1, 1)
    asm volatile("" ::: "memory");
    __builtin_amdgcn_s_barrier();
    XSTAGE(1, 4)
    asm volatile("s_waitcnt vmcnt(4)" ::: "memory");   // x2 landed
    __builtin_amdgcn_s_barrier();
    asm volatile("" ::: "memory");

    COMPUTE(2, 2)
    asm volatile("" ::: "memory");
    __builtin_amdgcn_s_barrier();
    XSTAGE(2, 5)
    asm volatile("s_waitcnt vmcnt(4)" ::: "memory");   // x3 landed
    __builtin_amdgcn_s_barrier();
    asm volatile("" ::: "memory");

    COMPUTE(3, 0)
    asm volatile("s_waitcnt vmcnt(2)" ::: "memory");   // x4 landed
    __builtin_amdgcn_s_barrier();
    asm volatile("" ::: "memory");

    COMPUTE(4, 1)
    asm volatile("s_waitcnt vmcnt(0)" ::: "memory");   // x5 landed
    __builtin_amdgcn_s_barrier();
    asm volatile("" ::: "memory");

    COMPUTE(5, 2)

#undef XSTAGE
#undef COMPUTE

    // ---- split-16 reduce through reused x-buffer LDS ----
    __syncthreads();                          // full drain (once, cheap here)
#pragma unroll
    for (int k = 0; k < NL; ++k)
        smem[XOFF + (g * NL + k) * 16 + r] = acc[k];
    __syncthreads();

    for (int o = tid; o < RB * NL; o += 256) {
        const int rr = o / NL, kk = o - rr * NL;
        float s = bias[kk];
#pragma unroll
        for (int gg = 0; gg < 16; ++gg)
            s += smem[XOFF + (gg * NL + kk) * 16 + rr];
        y[rowbase * NL + o] = s;
    }
}

// ===========================================================================
// Kernel 2: CRF llh. One wave per batch, no LDS. Exp-domain scan; lane j<17
// streams em column j straight from global (L2/L3-hit), double-buffered 8
// steps ahead with exp applied at prefetch. Renorm = exponent extract+ldexp.
// ===========================================================================
__device__ __forceinline__ float bcast(float v, int i) {
    return __uint_as_float(__builtin_amdgcn_readlane(__float_as_uint(v), i));
}

#define CRF_BODY(eem, PN)  \
    { float q0, q1, q2, q3;                                               \
      q0 = bcast(p,  0) * et[0];  q1 = bcast(p,  1) * et[1];              \
      q2 = bcast(p,  2) * et[2];  q3 = bcast(p,  3) * et[3];              \
      q0 = fmaf(bcast(p,  4), et[4],  q0); q1 = fmaf(bcast(p,  5), et[5],  q1); \
      q2 = fmaf(bcast(p,  6), et[6],  q2); q3 = fmaf(bcast(p,  7), et[7],  q3); \
      q0 = fmaf(bcast(p,  8), et[8],  q0); q1 = fmaf(bcast(p,  9), et[9],  q1); \
      q2 = fmaf(bcast(p, 10), et[10], q2); q3 = fmaf(bcast(p, 11), et[11], q3); \
      q0 = fmaf(bcast(p, 12), et[12], q0); q1 = fmaf(bcast(p, 13), et[13], q1); \
      q2 = fmaf(bcast(p, 14), et[14], q2); q3 = fmaf(bcast(p, 15), et[15], q3); \
      q0 = fmaf(bcast(p, 16), et[16], q0);                                \
      PN = ((q0 + q1) + (q2 + q3)) * (eem); }

#define CRF_STEP(eem)      { float pn_; CRF_BODY(eem, pn_); p = pn_; }
#define CRF_STEPG(eem, tt) { float pn_; CRF_BODY(eem, pn_); p = ((tt) < len) ? pn_ : p; }

__global__ __launch_bounds__(64) void crf_kernel(const float* __restrict__ emis,
                                                 const float* __restrict__ st_,
                                                 const float* __restrict__ en_,
                                                 const float* __restrict__ tr_,
                                                 const int* __restrict__ labels,
                                                 const int* __restrict__ mask,
                                                 float* __restrict__ llh) {
    const int b = blockIdx.x;
    const int l = threadIdx.x;
    const float* eb = emis + (size_t)b * TT * NL;
    const int*   lb = labels + b * TT;

    // ---- sequence length (prefix mask) ----
    int lenp = 0;
#pragma unroll
    for (int m = 0; m < 8; ++m) lenp += (mask[b * TT + l + 64 * m] != 0);
#pragma unroll
    for (int off = 32; off; off >>= 1) lenp += __shfl_down(lenp, off);
    const int len = __shfl(lenp, 0);

    // ---- numerator ----
    float np = 0.f;
#pragma unroll
    for (int m = 0; m < 8; ++m) {
        const int t = l + 64 * m;
        int tag = lb[t]; if ((unsigned)tag >= NL) tag = 0;
        if (t < len) {
            if (t == 0) {
                np += st_[tag] + eb[tag];
            } else {
                int tp = lb[t - 1]; if ((unsigned)tp >= NL) tp = 0;
                np += tr_[tp * NL + tag] + eb[t * NL + tag];
            }
            if (t == len - 1) np += en_[tag];
        }
    }
#pragma unroll
    for (int off = 32; off; off >>= 1) np += __shfl_down(np, off);
    const float num = __shfl(np, 0);

    // ---- denominator: exp-domain forward scan ----
    const bool act = (l < NL);
    const int  j   = act ? l : 0;

    float et[NL];
#pragma unroll
    for (int i = 0; i < NL; ++i) et[i] = act ? __expf(tr_[i * NL + j]) : 0.f;

    float p = act ? __expf(st_[j] + eb[j]) : 0.f;
    int   Mi = 0;

    float cur[8];
#pragma unroll
    for (int i = 0; i < 8; ++i) cur[i] = __expf(eb[(1 + i) * NL + j]);

    for (int t0 = 1; t0 < len; t0 += 8) {
        float nx[8];
#pragma unroll
        for (int i = 0; i < 8; ++i) {
            int tn = t0 + 8 + i; tn = (tn < TT) ? tn : (TT - 1);
            nx[i] = eb[tn * NL + j];             // issue; consumed next group
        }
        if (t0 + 8 <= len) {
            CRF_STEP(cur[0]); CRF_STEP(cur[1]); CRF_STEP(cur[2]); CRF_STEP(cur[3]);
            CRF_STEP(cur[4]); CRF_STEP(cur[5]); CRF_STEP(cur[6]); CRF_STEP(cur[7]);
        } else {
            CRF_STEPG(cur[0], t0 + 0); CRF_STEPG(cur[1], t0 + 1);
            CRF_STEPG(cur[2], t0 + 2); CRF_STEPG(cur[3], t0 + 3);
            CRF_STEPG(cur[4], t0 + 4); CRF_STEPG(cur[5], t0 + 5);
            CRF_STEPG(cur[6], t0 + 6); CRF_STEPG(cur[7], t0 + 7);
        }
        // renorm by p0 via exponent extraction (no log/rcp on critical path)
        const unsigned pb = (unsigned)__builtin_amdgcn_readlane((int)__float_as_uint(p), 0);
        const int e = (int)(pb >> 23) - 127;
        Mi += e;
        p = ldexpf(p, -e);
#pragma unroll
        for (int i = 0; i < 8; ++i) cur[i] = __expf(nx[i]);
    }

    float v = act ? p * __expf(en_[j]) : 0.f;
#pragma unroll
    for (int off = 32; off; off >>= 1) v += __shfl_down(v, off);

    if (l == 0) {
        const float denom = (float)Mi * 0.6931471805599453f + __logf(v);
        llh[b] = num - denom;
    }
}

// ===========================================================================
// Kernel 3: loss = -mean(llh)
// ===========================================================================
__global__ __launch_bounds__(64) void loss_kernel(const float* __restrict__ llh,
                                                  float* __restrict__ loss) {
    float v = llh[threadIdx.x];
#pragma unroll
    for (int off = 32; off; off >>= 1) v += __shfl_down(v, off);
    if (threadIdx.x == 0) loss[0] = -(v * (1.0f / BB));
}

// ===========================================================================
extern "C" void kernel_launch(void* const* d_in, const int* in_sizes, int n_in,
                              void* d_out, int out_size, void* d_ws, size_t ws_size,
                              hipStream_t stream) {
    const float* outputs = (const float*)d_in[0];
    const float* fc_w    = (const float*)d_in[1];
    const float* fc_b    = (const float*)d_in[2];
    const float* start_t = (const float*)d_in[3];
    const float* end_t   = (const float*)d_in[4];
    const float* trans   = (const float*)d_in[5];
    const int*   labels  = (const int*)d_in[6];
    const int*   mask    = (const int*)d_in[7];

    float* emis = (float*)d_out;
    float* loss = emis + (size_t)BB * TT * NL;
    float* llh  = (float*)d_ws;

    emis_kernel<<<(BB * TT) / RB, 256, 0, stream>>>(outputs, fc_w, fc_b, emis);
    crf_kernel<<<BB, 64, 0, stream>>>(emis, start_t, end_t, trans, labels, mask, llh);
    loss_kernel<<<1, 64, 0, stream>>>(llh, loss);
}

// Round 12
// 71.173 us; speedup vs baseline: 1.2821x; 1.2565x over previous
//
#include <hip/hip_runtime.h>

#define HID 768
#define NL  17
#define BB  64
#define TT  512

#define RB   16                  // emis rows per block
#define CK   128                 // emis K-chunk (floats)
#define NCH  6                   // HID / CK
#define WFL  (NL * HID)          // 13056 floats: all of w in LDS
#define XTF  (RB * CK)           // 2048 floats per x buffer
#define XOFF WFL                 // x buffers follow w

#define SEG  16                  // CRF segments per batch
#define SLEN 32                  // steps per segment
#define QST  352                 // ws floats per (b,s): 17*20 Q + Mi + pad

// ===========================================================================
// Kernel 1: emissions = outputs @ fc_w^T + fc_b  — UNCHANGED from R11 (best:
// ~55 us; counted-vmcnt gload_lds pipeline). Left identical for attribution.
// ===========================================================================
__device__ __forceinline__ void gload16(const float* g, float* l) {
    __builtin_amdgcn_global_load_lds(
        (const __attribute__((address_space(1))) float*)g,
        (__attribute__((address_space(3))) float*)l, 16, 0, 0);
}

__global__ __launch_bounds__(256) void emis_kernel(const float* __restrict__ x,
                                                   const float* __restrict__ w,
                                                   const float* __restrict__ bias,
                                                   float* __restrict__ y) {
    __shared__ float smem[WFL + 3 * XTF];     // 76.8 KB

    const int tid = threadIdx.x;
    const int wub = tid & ~63;
    const size_t rowbase = (size_t)blockIdx.x * RB;

#pragma unroll
    for (int j = 0; j < 13; ++j) {
        const int G = tid + 256 * j;
        if (G < WFL / 4)
            gload16(w + 4 * (size_t)G, &smem[4 * (wub + 256 * j)]);
    }
    __builtin_amdgcn_sched_barrier(0);

#define XSTAGE(buf, c)                                                        \
    {                                                                         \
        _Pragma("unroll")                                                     \
        for (int i = 0; i < 2; ++i) {                                         \
            const int d = tid + 256 * i;                                      \
            const int rr_ = d >> 5, jg = d & 31;                              \
            gload16(x + (rowbase + rr_) * HID + (c) * CK + ((jg ^ (rr_ & 7)) << 2), \
                    &smem[XOFF + (buf) * XTF + 4 * (wub + 256 * i)]);         \
        }                                                                     \
        __builtin_amdgcn_sched_barrier(0);                                    \
    }

    XSTAGE(0, 0) XSTAGE(1, 1) XSTAGE(2, 2)

    float acc[NL];
#pragma unroll
    for (int k = 0; k < NL; ++k) acc[k] = 0.f;

    const int r = tid & 15;
    const int g = tid >> 4;
    const int q = r & 7;

    asm volatile("s_waitcnt vmcnt(4)" ::: "memory");
    __builtin_amdgcn_s_barrier();
    asm volatile("" ::: "memory");

#define COMPUTE(c, buf)                                                       \
    {                                                                         \
        const float* xb = &smem[XOFF + (buf) * XTF + r * CK];                 \
        const float4 xf0 = *reinterpret_cast<const float4*>(xb + (((2 * g)     ^ q) << 2)); \
        const float4 xf1 = *reinterpret_cast<const float4*>(xb + (((2 * g + 1) ^ q) << 2)); \
        _Pragma("unroll")                                                     \
        for (int k = 0; k < NL; ++k) {                                        \
            const float* wk = &smem[k * HID + (c) * CK + g * 8];              \
            const float4 wa = *reinterpret_cast<const float4*>(wk);           \
            const float4 wc = *reinterpret_cast<const float4*>(wk + 4);       \
            float s0 = fmaf(xf0.x, wa.x, acc[k]);                             \
            float s1 = xf0.y * wa.y;                                          \
            s0 = fmaf(xf0.z, wa.z, s0);                                       \
            s1 = fmaf(xf0.w, wa.w, s1);                                       \
            s0 = fmaf(xf1.x, wc.x, s0);                                       \
            s1 = fmaf(xf1.y, wc.y, s1);                                       \
            s0 = fmaf(xf1.z, wc.z, s0);                                       \
            s1 = fmaf(xf1.w, wc.w, s1);                                       \
            acc[k] = s0 + s1;                                                 \
        }                                                                     \
    }

    COMPUTE(0, 0)
    asm volatile("" ::: "memory");
    __builtin_amdgcn_s_barrier();
    XSTAGE(0, 3)
    asm volatile("s_waitcnt vmcnt(4)" ::: "memory");
    __builtin_amdgcn_s_barrier();
    asm volatile("" ::: "memory");

    COMPUTE(1, 1)
    asm volatile("" ::: "memory");
    __builtin_amdgcn_s_barrier();
    XSTAGE(1, 4)
    asm volatile("s_waitcnt vmcnt(4)" ::: "memory");
    __builtin_amdgcn_s_barrier();
    asm volatile("" ::: "memory");

    COMPUTE(2, 2)
    asm volatile("" ::: "memory");
    __builtin_amdgcn_s_barrier();
    XSTAGE(2, 5)
    asm volatile("s_waitcnt vmcnt(4)" ::: "memory");
    __builtin_amdgcn_s_barrier();
    asm volatile("" ::: "memory");

    COMPUTE(3, 0)
    asm volatile("s_waitcnt vmcnt(2)" ::: "memory");
    __builtin_amdgcn_s_barrier();
    asm volatile("" ::: "memory");

    COMPUTE(4, 1)
    asm volatile("s_waitcnt vmcnt(0)" ::: "memory");
    __builtin_amdgcn_s_barrier();
    asm volatile("" ::: "memory");

    COMPUTE(5, 2)

#undef XSTAGE
#undef COMPUTE

    __syncthreads();
#pragma unroll
    for (int k = 0; k < NL; ++k)
        smem[XOFF + (g * NL + k) * 16 + r] = acc[k];
    __syncthreads();

    for (int o = tid; o < RB * NL; o += 256) {
        const int rr = o / NL, kk = o - rr * NL;
        float s = bias[kk];
#pragma unroll
        for (int gg = 0; gg < 16; ++gg)
            s += smem[XOFF + (gg * NL + kk) * 16 + rr];
        y[rowbase * NL + o] = s;
    }
}

// ===========================================================================
// Kernel 2a: CRF segment scan. Block (b,s) = 1 wave computes the 17x17 matrix
// Q_s = prod_{t in seg} diag(e_t) A^T over 32 steps. Transposed double-buffer
// Q^T in LDS (QT[j][i] = Q[i][j]): reads are contiguous 17-float rows
// (broadcast x3 lanes), writes 6 scattered b32. Lane l<51: i = l/3 (out row),
// m = l%3 (col group {0-5,6-11,12-16(+17 scratch)}). A-column exp(tr[k][i])
// lives in 17 regs/lane. No barriers (single wave). Exponent renorm every 2
// steps folded into next step's scalar; pending scale applied at store.
// ===========================================================================
__global__ __launch_bounds__(64) void crf_scan_kernel(const float* __restrict__ emis,
                                                      const float* __restrict__ tr_,
                                                      const int* __restrict__ mask,
                                                      float* __restrict__ ws) {
    __shared__ float QT[2][18][20];            // [buf][col j (0..17)][row i]

    const int bs = blockIdx.x;
    const int b  = bs >> 4;
    const int s  = bs & 15;
    const int l  = threadIdx.x;
    const float* eb = emis + (size_t)b * TT * NL;

    // ---- sequence length (prefix mask) ----
    int lenp = 0;
#pragma unroll
    for (int m = 0; m < 8; ++m) lenp += (mask[b * TT + l + 64 * m] != 0);
#pragma unroll
    for (int off = 32; off; off >>= 1) lenp += __shfl_down(lenp, off);
    const int len = __shfl(lenp, 0);

    const int t0    = 1 + SLEN * s;
    const int tend  = min(t0 + SLEN, len);
    const int trips = (tend > t0) ? (tend - t0) : 0;

    const bool act = (l < 51);
    const int  i   = act ? (l / 3) : 0;        // output row 0..16
    const int  m   = act ? (l - 3 * (l / 3)) : 0;
    const int  j0  = 6 * m;                    // 0, 6, 12

    // init Q = I (transposed): QT[j][i] = (i==j); col 17 scratch = 0
    if (act) {
#pragma unroll
        for (int jj = 0; jj < 6; ++jj)
            QT[0][j0 + jj][i] = (i == j0 + jj) ? 1.f : 0.f;
    }

    // A column i: at[k] = exp(tr[k][i])
    float at[17];
#pragma unroll
    for (int k = 0; k < 17; ++k) at[k] = __expf(tr_[k * NL + i]);

    float psc = 1.f;
    int   Mi  = 0;
    float emv = (trips > 0) ? eb[t0 * NL + i] : 0.f;
    int   t   = t0;

#define QSTEP(SRC, DST, TCUR)                                                 \
    {                                                                         \
        const float e_ = __expf(emv) * psc;  psc = 1.f;                       \
        const int tn_ = ((TCUR) + 1 < tend) ? ((TCUR) + 1) : (TT - 1);        \
        const float env_ = eb[tn_ * NL + i];                                  \
        float o[6];                                                           \
        _Pragma("unroll")                                                     \
        for (int jj = 0; jj < 6; ++jj) {                                      \
            const float* qr = &QT[SRC][j0 + jj][0];                           \
            const float4 a0 = *reinterpret_cast<const float4*>(qr);           \
            const float4 a1 = *reinterpret_cast<const float4*>(qr + 4);       \
            const float4 a2 = *reinterpret_cast<const float4*>(qr + 8);       \
            const float4 a3 = *reinterpret_cast<const float4*>(qr + 12);      \
            const float aL  = qr[16];                                         \
            float u0 = at[0] * a0.x, u1 = at[1] * a0.y;                       \
            float u2 = at[2] * a0.z, u3 = at[3] * a0.w;                       \
            u0 = fmaf(at[4],  a1.x, u0); u1 = fmaf(at[5],  a1.y, u1);         \
            u2 = fmaf(at[6],  a1.z, u2); u3 = fmaf(at[7],  a1.w, u3);         \
            u0 = fmaf(at[8],  a2.x, u0); u1 = fmaf(at[9],  a2.y, u1);         \
            u2 = fmaf(at[10], a2.z, u2); u3 = fmaf(at[11], a2.w, u3);         \
            u0 = fmaf(at[12], a3.x, u0); u1 = fmaf(at[13], a3.y, u1);         \
            u2 = fmaf(at[14], a3.z, u2); u3 = fmaf(at[15], a3.w, u3);         \
            u0 = fmaf(at[16], aL,   u0);                                      \
            o[jj] = (u0 + u1) + (u2 + u3);                                    \
        }                                                                     \
        if (act) {                                                            \
            _Pragma("unroll")                                                 \
            for (int jj = 0; jj < 6; ++jj)                                    \
                QT[DST][j0 + jj][i] = e_ * o[jj];                             \
        }                                                                     \
        emv = env_;                                                           \
    }

    for (int pp = 0; pp < (trips >> 1); ++pp) {
        QSTEP(0, 1, t)
        QSTEP(1, 0, t + 1)
        t += 2;
        // renorm: factor 2^-E out of Q (folded into next step / store)
        const float q00 = QT[0][0][0];
        const int E = (int)((__float_as_uint(q00) >> 23) & 0xff) - 127;
        Mi += E;
        psc = __builtin_amdgcn_ldexpf(1.f, -E);
    }
    int sbuf = 0;
    if (trips & 1) { QSTEP(0, 1, t) sbuf = 1; }
#undef QSTEP

    // store Q rows (un-transpose) + Mi
    if (act) {
        float* dst = ws + (size_t)bs * QST + i * 20;
#pragma unroll
        for (int jj = 0; jj < 6; ++jj) {
            const int j = j0 + jj;
            if (j < 17) dst[j] = psc * QT[sbuf][j][i];
        }
    }
    if (l == 0) ws[(size_t)bs * QST + 340] = (float)Mi;
}

// ===========================================================================
// Kernel 2b: combine — per batch: numerator + p0, then 16 matrix applies
// p <- Q_s p (readlane broadcast FMA), exponent renorm per segment.
// ===========================================================================
__device__ __forceinline__ float bcast(float v, int i) {
    return __uint_as_float(__builtin_amdgcn_readlane(__float_as_uint(v), i));
}

__global__ __launch_bounds__(64) void crf_combine_kernel(const float* __restrict__ emis,
                                                         const float* __restrict__ st_,
                                                         const float* __restrict__ en_,
                                                         const float* __restrict__ tr_,
                                                         const int* __restrict__ labels,
                                                         const int* __restrict__ mask,
                                                         const float* __restrict__ ws,
                                                         float* __restrict__ llh) {
    const int b = blockIdx.x;
    const int l = threadIdx.x;
    const float* eb = emis + (size_t)b * TT * NL;
    const int*   lb = labels + b * TT;

    // ---- sequence length ----
    int lenp = 0;
#pragma unroll
    for (int m = 0; m < 8; ++m) lenp += (mask[b * TT + l + 64 * m] != 0);
#pragma unroll
    for (int off = 32; off; off >>= 1) lenp += __shfl_down(lenp, off);
    const int len = __shfl(lenp, 0);

    // ---- numerator ----
    float np = 0.f;
#pragma unroll
    for (int m = 0; m < 8; ++m) {
        const int t = l + 64 * m;
        int tag = lb[t]; if ((unsigned)tag >= NL) tag = 0;
        if (t < len) {
            if (t == 0) {
                np += st_[tag] + eb[tag];
            } else {
                int tp = lb[t - 1]; if ((unsigned)tp >= NL) tp = 0;
                np += tr_[tp * NL + tag] + eb[t * NL + tag];
            }
            if (t == len - 1) np += en_[tag];
        }
    }
#pragma unroll
    for (int off = 32; off; off >>= 1) np += __shfl_down(np, off);
    const float num = __shfl(np, 0);

    // ---- denominator: p0 then 16 matrix applies ----
    const bool act = (l < NL);
    const int  j   = act ? l : 0;

    float p  = act ? __expf(st_[j] + eb[j]) : 0.f;
    int   Mi = 0;

    for (int s = 0; s < SEG; ++s) {
        const float* qs = ws + (size_t)(b * SEG + s) * QST;
        const float* qr = qs + j * 20;         // my Q row (lane j)
        const float4 a0 = *reinterpret_cast<const float4*>(qr);
        const float4 a1 = *reinterpret_cast<const float4*>(qr + 4);
        const float4 a2 = *reinterpret_cast<const float4*>(qr + 8);
        const float4 a3 = *reinterpret_cast<const float4*>(qr + 12);
        const float  aL = qr[16];
        const float  Msc = qs[340];

        float u0 = a0.x * bcast(p, 0),  u1 = a0.y * bcast(p, 1);
        float u2 = a0.z * bcast(p, 2),  u3 = a0.w * bcast(p, 3);
        u0 = fmaf(a1.x, bcast(p, 4),  u0); u1 = fmaf(a1.y, bcast(p, 5),  u1);
        u2 = fmaf(a1.z, bcast(p, 6),  u2); u3 = fmaf(a1.w, bcast(p, 7),  u3);
        u0 = fmaf(a2.x, bcast(p, 8),  u0); u1 = fmaf(a2.y, bcast(p, 9),  u1);
        u2 = fmaf(a2.z, bcast(p, 10), u2); u3 = fmaf(a2.w, bcast(p, 11), u3);
        u0 = fmaf(a3.x, bcast(p, 12), u0); u1 = fmaf(a3.y, bcast(p, 13), u1);
        u2 = fmaf(a3.z, bcast(p, 14), u2); u3 = fmaf(a3.w, bcast(p, 15), u3);
        u0 = fmaf(aL,   bcast(p, 16), u0);
        p = act ? ((u0 + u1) + (u2 + u3)) : 0.f;
        Mi += (int)Msc;

        // exponent renorm of p
        const unsigned pb = (unsigned)__builtin_amdgcn_readlane((int)__float_as_uint(p), 0);
        const int e = (int)((pb >> 23) & 0xff) - 127;
        Mi += e;
        p = __builtin_amdgcn_ldexpf(p, -e);
    }

    float v = act ? p * __expf(en_[j]) : 0.f;
#pragma unroll
    for (int off = 32; off; off >>= 1) v += __shfl_down(v, off);

    if (l == 0) {
        const float denom = (float)Mi * 0.6931471805599453f + __logf(v);
        llh[b] = num - denom;
    }
}

// ===========================================================================
// Kernel 3: loss = -mean(llh)
// ===========================================================================
__global__ __launch_bounds__(64) void loss_kernel(const float* __restrict__ llh,
                                                  float* __restrict__ loss) {
    float v = llh[threadIdx.x];
#pragma unroll
    for (int off = 32; off; off >>= 1) v += __shfl_down(v, off);
    if (threadIdx.x == 0) loss[0] = -(v * (1.0f / BB));
}

// ===========================================================================
extern "C" void kernel_launch(void* const* d_in, const int* in_sizes, int n_in,
                              void* d_out, int out_size, void* d_ws, size_t ws_size,
                              hipStream_t stream) {
    const float* outputs = (const float*)d_in[0];
    const float* fc_w    = (const float*)d_in[1];
    const float* fc_b    = (const float*)d_in[2];
    const float* start_t = (const float*)d_in[3];
    const float* end_t   = (const float*)d_in[4];
    const float* trans   = (const float*)d_in[5];
    const int*   labels  = (const int*)d_in[6];
    const int*   mask    = (const int*)d_in[7];

    float* emis = (float*)d_out;
    float* loss = emis + (size_t)BB * TT * NL;
    float* ws   = (float*)d_ws;                       // BB*SEG*QST floats
    float* llh  = ws + (size_t)BB * SEG * QST;        // 64 floats after

    emis_kernel<<<(BB * TT) / RB, 256, 0, stream>>>(outputs, fc_w, fc_b, emis);
    crf_scan_kernel<<<BB * SEG, 64, 0, stream>>>(emis, trans, mask, ws);
    crf_combine_kernel<<<BB, 64, 0, stream>>>(emis, start_t, end_t, trans,
                                              labels, mask, ws, llh);
    loss_kernel<<<1, 64, 0, stream>>>(llh, loss);
}